// Round 3
// baseline (135.860 us; speedup 1.0000x reference)
//
#include <hip/hip_runtime.h>
#include <math.h>

#define N_TOTAL 8192
#define HALF    4096
#define EMBED   192
#define BT      128                 // block tile (128x128 pairs per block)
#define NT      (N_TOTAL / BT)      // 64 tiles per dim
#define NBLK    (NT * (NT + 1) / 2) // 2080 upper-triangle blocks

typedef short bf16x8 __attribute__((ext_vector_type(8)));
typedef float f32x4  __attribute__((ext_vector_type(4)));

// ---------------- ws layout (bytes) ----------------
// [0]     double sumsq_all
// [8]     double acc (signed kernel sum)
// [16]    float  colsum[192]
// [784]   float  inv_c  ( = 1/(16*bandwidth) )
// [800]   float  sq[8192]        (TOTAL-order row sumsq)
// [33568] ushort xb[8192*192]    (TOTAL-order bf16 copy of x)

__device__ __forceinline__ unsigned pack2_bf16(float a, float b) {
    unsigned ua = __float_as_uint(a), ub = __float_as_uint(b);
    unsigned ha = (ua + 0x7FFFu + ((ua >> 16) & 1u)) >> 16;   // RNE
    unsigned hb = (ub + 0x7FFFu + ((ub >> 16) & 1u)) >> 16;
    return ha | (hb << 16);
}

// Fused pass 1: row sumsq + bf16 convert (total-order) + column sums + total sumsq.
// 256 blocks x 32 rows; 8 threads per row, 24 floats (6 float4) per thread.
__global__ __launch_bounds__(256) void prep(
    const float* __restrict__ x, unsigned short* __restrict__ xb,
    float* __restrict__ sq, float* __restrict__ colsum,
    double* __restrict__ sumsq_all) {
    __shared__ float  ls_col[EMBED];
    __shared__ double ls_sq[4];
    int t = threadIdx.x;
    if (t < EMBED) ls_col[t] = 0.f;
    __syncthreads();

    int r   = blockIdx.x * 32 + (t >> 3);
    int sub = t & 7;
    int g   = (r & 1) ? (HALF + (r >> 1)) : (r >> 1);
    const float*    src = x  + (size_t)r * EMBED;
    unsigned short* dst = xb + (size_t)g * EMBED;

    float  s = 0.f;
    float4 v[6];
#pragma unroll
    for (int m = 0; m < 6; ++m) {
        v[m] = *(const float4*)(src + (sub + 8 * m) * 4);
        s += v[m].x * v[m].x + v[m].y * v[m].y + v[m].z * v[m].z + v[m].w * v[m].w;
    }
#pragma unroll
    for (int m = 0; m < 6; ++m) {
        uint2 o;
        o.x = pack2_bf16(v[m].x, v[m].y);
        o.y = pack2_bf16(v[m].z, v[m].w);
        *(uint2*)(dst + (sub + 8 * m) * 4) = o;
    }
    // row sumsq: reduce over lane bits 0..2 (the 8 subs of one row)
    s += __shfl_xor(s, 1, 64);
    s += __shfl_xor(s, 2, 64);
    s += __shfl_xor(s, 4, 64);
    if (sub == 0) sq[g] = s;
    // column sums into LDS
#pragma unroll
    for (int m = 0; m < 6; ++m) {
        int c = (sub + 8 * m) * 4;
        atomicAdd(&ls_col[c + 0], v[m].x);
        atomicAdd(&ls_col[c + 1], v[m].y);
        atomicAdd(&ls_col[c + 2], v[m].z);
        atomicAdd(&ls_col[c + 3], v[m].w);
    }
    // wave total of row sums (only sub==0 lanes contribute, reduce lane bits 3..5)
    float bs = (sub == 0) ? s : 0.f;
    bs += __shfl_xor(bs, 8, 64);
    bs += __shfl_xor(bs, 16, 64);
    bs += __shfl_xor(bs, 32, 64);
    if ((t & 63) == 0) ls_sq[t >> 6] = (double)bs;
    __syncthreads();
    if (t < EMBED) atomicAdd(&colsum[t], ls_col[t]);
    if (t == 0) atomicAdd(sumsq_all, ls_sq[0] + ls_sq[1] + ls_sq[2] + ls_sq[3]);
}

// Pass 2: bandwidth via closed form, parallel (256 threads, one block).
__global__ __launch_bounds__(256) void finalize_bw(
    const float* __restrict__ colsum, const double* __restrict__ sumsq_all,
    float* __restrict__ inv_c) {
    __shared__ double ws[4];
    int t = threadIdx.x;
    double c = (t < EMBED) ? (double)colsum[t] : 0.0;
    double p = c * c;
#pragma unroll
    for (int off = 32; off; off >>= 1) p += __shfl_down(p, off, 64);
    if ((t & 63) == 0) ws[t >> 6] = p;
    __syncthreads();
    if (t == 0) {
        double s2 = ws[0] + ws[1] + ws[2] + ws[3];
        double n  = (double)N_TOTAL;
        double sumL2 = 2.0 * n * (*sumsq_all) - 2.0 * s2;
        double bw = sumL2 / (n * n - n) / 4.0;   // / KERNEL_MUL^(KERNEL_NUM//2)
        *inv_c = (float)(1.0 / (16.0 * bw));
    }
}

// Pass 3: MFMA Gram + fused 5-scale Gaussian epilogue, upper triangle.
// No LDS tiles: fragments load straight from global (xb is L2-resident, 3 MB).
// Each of the 4 kg-groups covers 16B of a row's 64B cache line -> lines fully used.
__global__ __launch_bounds__(256, 3) void mmd_mfma(
    const unsigned short* __restrict__ xb, const float* __restrict__ sq,
    const float* __restrict__ inv_c, double* __restrict__ acc_out) {
    // decode upper-triangle block index
    int id = blockIdx.x, bi = 0;
    while (id >= NT - bi) { id -= NT - bi; ++bi; }
    int bj = bi + id;
    int I0 = bi * BT, J0 = bj * BT;

    __shared__ double wred[4];

    int t = threadIdx.x, lane = t & 63, wid = t >> 6;
    int wy = (wid >> 1) * 64, wx = (wid & 1) * 64;
    int lo = lane & 15, kg = lane >> 4;   // fragment row / k-group

    const unsigned short* pA = xb + (size_t)(I0 + wy + lo) * EMBED + kg * 8;
    const unsigned short* pB = xb + (size_t)(J0 + wx + lo) * EMBED + kg * 8;

    f32x4 acc[4][4];
#pragma unroll
    for (int i = 0; i < 4; ++i)
#pragma unroll
        for (int j = 0; j < 4; ++j) acc[i][j] = (f32x4)(0.f);

#pragma unroll
    for (int kk = 0; kk < EMBED; kk += 32) {
        bf16x8 a[4], b[4];
#pragma unroll
        for (int i = 0; i < 4; ++i) a[i] = *(const bf16x8*)(pA + i * 16 * EMBED + kk);
#pragma unroll
        for (int j = 0; j < 4; ++j) b[j] = *(const bf16x8*)(pB + j * 16 * EMBED + kk);
#pragma unroll
        for (int i = 0; i < 4; ++i)
#pragma unroll
            for (int j = 0; j < 4; ++j)
                acc[i][j] = __builtin_amdgcn_mfma_f32_16x16x32_bf16(a[i], b[j], acc[i][j], 0, 0, 0);
    }

    // epilogue: C/D layout col=lane&15, row=(lane>>4)*4+reg (m89-verified)
    const float cc = *inv_c;
    int gi0 = I0 + wy + kg * 4;
    int gj0 = J0 + wx + lo;
    float sqi[4][4], sqj[4];
#pragma unroll
    for (int i = 0; i < 4; ++i)
#pragma unroll
        for (int r = 0; r < 4; ++r) sqi[i][r] = sq[gi0 + i * 16 + r];
#pragma unroll
    for (int j = 0; j < 4; ++j) sqj[j] = sq[gj0 + j * 16];

    float sgn  = ((bi < NT / 2) == (bj < NT / 2)) ? 1.f : -1.f;
    float tsum = 0.f;
    if (bi != bj) {
        // off-diagonal: uniform weight 2, factored out
#pragma unroll
        for (int i = 0; i < 4; ++i)
#pragma unroll
            for (int j = 0; j < 4; ++j)
#pragma unroll
                for (int r = 0; r < 4; ++r) {
                    float L2 = sqi[i][r] + sqj[j] - 2.f * acc[i][j][r];
                    L2 = fmaxf(L2, 0.f);
                    float u   = __expf(-L2 * cc);
                    float u2  = u * u;
                    float u4  = u2 * u2;
                    float u8  = u4 * u4;
                    float u16 = u8 * u8;
                    tsum += (u + u2 + u4 + u8 + u16);
                }
        tsum *= 2.f;
    } else {
#pragma unroll
        for (int i = 0; i < 4; ++i)
#pragma unroll
            for (int j = 0; j < 4; ++j)
#pragma unroll
                for (int r = 0; r < 4; ++r) {
                    int gi = gi0 + i * 16 + r, gj = gj0 + j * 16;
                    float w = (gi < gj) ? 2.f : ((gi == gj) ? 1.f : 0.f);
                    float L2 = sqi[i][r] + sqj[j] - 2.f * acc[i][j][r];
                    L2 = fmaxf(L2, 0.f);
                    float u   = __expf(-L2 * cc);
                    float u2  = u * u;
                    float u4  = u2 * u2;
                    float u8  = u4 * u4;
                    float u16 = u8 * u8;
                    tsum += w * (u + u2 + u4 + u8 + u16);
                }
    }
    tsum *= sgn;

#pragma unroll
    for (int off = 32; off; off >>= 1) tsum += __shfl_down(tsum, off, 64);
    if (lane == 0) wred[wid] = (double)tsum;
    __syncthreads();
    if (t == 0) atomicAdd(acc_out, wred[0] + wred[1] + wred[2] + wred[3]);
}

__global__ void finalize_loss(const double* __restrict__ acc, float* __restrict__ out) {
    if (threadIdx.x == 0 && blockIdx.x == 0)
        out[0] = (float)(*acc / ((double)HALF * (double)HALF));
}

extern "C" void kernel_launch(void* const* d_in, const int* in_sizes, int n_in,
                              void* d_out, int out_size, void* d_ws, size_t ws_size,
                              hipStream_t stream) {
    const float* x = (const float*)d_in[0];   // label / genre_label unused by reference

    double*         d_sumsq  = (double*)d_ws;
    double*         d_acc    = (double*)d_ws + 1;
    float*          d_colsum = (float*)((char*)d_ws + 16);
    float*          d_invc   = (float*)((char*)d_ws + 784);
    float*          d_sq     = (float*)((char*)d_ws + 800);
    unsigned short* d_xb     = (unsigned short*)((char*)d_ws + 33568);

    hipMemsetAsync(d_ws, 0, 800, stream);   // zero accumulators

    prep<<<N_TOTAL / 32, 256, 0, stream>>>(x, d_xb, d_sq, d_colsum, d_sumsq);
    finalize_bw<<<1, 256, 0, stream>>>(d_colsum, d_sumsq, d_invc);
    mmd_mfma<<<NBLK, 256, 0, stream>>>(d_xb, d_sq, d_invc, d_acc);
    finalize_loss<<<1, 1, 0, stream>>>(d_acc, (float*)d_out);
}

// Round 4
// 121.860 us; speedup vs baseline: 1.1149x; 1.1149x over previous
//
#include <hip/hip_runtime.h>
#include <math.h>

#define N_TOTAL 8192
#define HALF    4096
#define EMBED   192
#define BT      128                 // block tile (128x128 pairs)
#define NT      (N_TOTAL / BT)      // 64
#define NBLK    (NT * (NT + 1) / 2) // 2080 upper-triangle blocks
#define KC      64                  // K chunk; 3 chunks of 64
#define NPREP   256                 // prep blocks
#define LOG2E   1.4426950408889634f

typedef short          bf16x8 __attribute__((ext_vector_type(8)));
typedef float          f32x4  __attribute__((ext_vector_type(4)));
typedef unsigned short ushort_t;

// ---------------- ws layout (bytes) ----------------
// [0]       int    counter        (zeroed by memset each launch)
// [8]       float  ccl  ( = log2e / (16*bandwidth) )
// [1024]    float  sq[8192]                  -> 33792
// [33792]   ushort xb[8192*192]   (3 MB)     -> 3179520
// [3179520] float  colpart[256*192]          -> 3376128
// [3376128] double sqpart[256]               -> 3378176
// [3378176] double accpart[2080]             -> 3394816

__device__ __forceinline__ unsigned pack2_bf16(float a, float b) {
    unsigned ua = __float_as_uint(a), ub = __float_as_uint(b);
    unsigned ha = (ua + 0x7FFFu + ((ua >> 16) & 1u)) >> 16;   // RNE
    unsigned hb = (ub + 0x7FFFu + ((ub >> 16) & 1u)) >> 16;
    return ha | (hb << 16);
}

// Pass 1: bf16 convert (total-order) + row sumsq + per-block column partials
// + per-block sumsq partial. NO global atomics except the completion counter;
// last-arriving block computes the bandwidth constant.
__global__ __launch_bounds__(256) void prep(
    const float* __restrict__ x, ushort_t* __restrict__ xb,
    float* __restrict__ sq, float* __restrict__ colpart,
    double* __restrict__ sqpart, int* __restrict__ counter,
    float* __restrict__ ccl_out) {
    __shared__ float4 lscol[4][48];
    __shared__ double lssq[4];
    __shared__ int    lastflag;
    __shared__ double red[4][2];

    int t = threadIdx.x, b = blockIdx.x;
    int lane = t & 63, w = t >> 6;
    int r = b * 32 + (t >> 3), sub = t & 7;
    int g = (r & 1) ? (HALF + (r >> 1)) : (r >> 1);
    const float* src = x  + (size_t)r * EMBED;
    ushort_t*    dst = xb + (size_t)g * EMBED;

    float  s = 0.f;
    float4 v[6];
#pragma unroll
    for (int m = 0; m < 6; ++m) {
        v[m] = *(const float4*)(src + (sub + 8 * m) * 4);
        s += v[m].x * v[m].x + v[m].y * v[m].y + v[m].z * v[m].z + v[m].w * v[m].w;
    }
#pragma unroll
    for (int m = 0; m < 6; ++m) {
        uint2 o;
        o.x = pack2_bf16(v[m].x, v[m].y);
        o.y = pack2_bf16(v[m].z, v[m].w);
        *(uint2*)(dst + (sub + 8 * m) * 4) = o;
    }
    // row sumsq: reduce over lane bits 0..2 (8 subs of one row)
    s += __shfl_xor(s, 1, 64);
    s += __shfl_xor(s, 2, 64);
    s += __shfl_xor(s, 4, 64);
    if (sub == 0) sq[g] = s;
    // column partials: butterfly over lane bits 3..5 (the wave's 8 rows)
#pragma unroll
    for (int m = 0; m < 6; ++m) {
#pragma unroll
        for (int off = 8; off <= 32; off <<= 1) {
            v[m].x += __shfl_xor(v[m].x, off, 64);
            v[m].y += __shfl_xor(v[m].y, off, 64);
            v[m].z += __shfl_xor(v[m].z, off, 64);
            v[m].w += __shfl_xor(v[m].w, off, 64);
        }
    }
    if (lane < 8) {
#pragma unroll
        for (int m = 0; m < 6; ++m) lscol[w][lane + 8 * m] = v[m];
    }
    // wave total of row sums (lanes with sub==0 carry row totals)
    float bs = (sub == 0) ? s : 0.f;
    bs += __shfl_xor(bs, 8, 64);
    bs += __shfl_xor(bs, 16, 64);
    bs += __shfl_xor(bs, 32, 64);
    if (lane == 0) lssq[w] = (double)bs;
    __syncthreads();
    if (t < 48) {
        float4 a = lscol[0][t], b4 = lscol[1][t], c4 = lscol[2][t], d4 = lscol[3][t];
        float4 o;
        o.x = a.x + b4.x + c4.x + d4.x;
        o.y = a.y + b4.y + c4.y + d4.y;
        o.z = a.z + b4.z + c4.z + d4.z;
        o.w = a.w + b4.w + c4.w + d4.w;
        ((float4*)colpart)[b * 48 + t] = o;
    }
    if (t == 0) sqpart[b] = lssq[0] + lssq[1] + lssq[2] + lssq[3];

    // completion counter; last block finalizes the bandwidth constant
    __threadfence();
    __syncthreads();
    if (t == 0) {
        int old = atomicAdd(counter, 1);
        lastflag = (old == NPREP - 1);
    }
    __syncthreads();
    if (!lastflag) return;
    __threadfence();   // acquire: invalidate L1 before reading peers' partials

    double p = 0.0;    // sum over cols of colsum^2
    if (t < EMBED) {
        float cs = 0.f;
        for (int bb = 0; bb < NPREP; ++bb) cs += colpart[bb * EMBED + t];
        p = (double)cs * (double)cs;
    }
    double z = sqpart[t];   // t < 256 == NPREP
#pragma unroll
    for (int off = 32; off; off >>= 1) {
        p += __shfl_down(p, off, 64);
        z += __shfl_down(z, off, 64);
    }
    if (lane == 0) { red[w][0] = p; red[w][1] = z; }
    __syncthreads();
    if (t == 0) {
        double P = red[0][0] + red[1][0] + red[2][0] + red[3][0];
        double S = red[0][1] + red[1][1] + red[2][1] + red[3][1];
        double n = (double)N_TOTAL;
        double sumL2 = 2.0 * n * S - 2.0 * P;
        double bw = sumL2 / (n * n - n) / 4.0;   // / KERNEL_MUL^(KERNEL_NUM//2)
        *ccl_out = (float)((double)LOG2E / (16.0 * bw));
    }
}

// Pass 2: MFMA Gram + fused 5-scale Gaussian epilogue, upper triangle.
// Async global->LDS staging (width 16) with XOR-swizzled source so the
// unpadded 128B-row LDS layout gives conflict-free (2-way) ds_read_b128.
__global__ __launch_bounds__(256, 4) void mmd_mfma(
    const ushort_t* __restrict__ xb, const float* __restrict__ sq,
    const float* __restrict__ ccl_p, double* __restrict__ accpart) {
    int id = blockIdx.x, bi = 0;
    while (id >= NT - bi) { id -= NT - bi; ++bi; }
    int bj = bi + id;
    int I0 = bi * BT, J0 = bj * BT;

    __shared__ ushort_t As[BT][KC];   // 16 KB, row = 128 B (32 banks) + swizzle
    __shared__ ushort_t Bs[BT][KC];   // 16 KB
    __shared__ double   wred[4];

    int t = threadIdx.x, lane = t & 63, wid = t >> 6;
    int wy = (wid >> 1) * 64, wx = (wid & 1) * 64;
    int lo = lane & 15, kg = lane >> 4;

    // staging lane constants: lane covers row (l>>3) of an 8-row group,
    // source 16B-chunk is XOR-permuted so LDS[r][p] = global[r][p ^ (r&7)]
    int srow = lane >> 3;
    int sch  = (lane & 7) ^ srow;

    f32x4 acc[4][4];
#pragma unroll
    for (int i = 0; i < 4; ++i)
#pragma unroll
        for (int j = 0; j < 4; ++j) acc[i][j] = (f32x4)(0.f);

    const float ccl = *ccl_p;

    for (int c = 0; c < 3; ++c) {
        int kc0 = c * KC;
#pragma unroll
        for (int qi = 0; qi < 8; ++qi) {
            int q    = wid * 8 + qi;       // 32 wave-issues: 16 for A, 16 for B
            int row0 = (q & 15) * 8;
            int grow = ((q >> 4) ? J0 : I0) + row0 + srow;
            const ushort_t* gp = xb + (size_t)grow * EMBED + kc0 + sch * 8;
            ushort_t* lp = ((q >> 4) ? &Bs[0][0] : &As[0][0]) + row0 * KC;
            __builtin_amdgcn_global_load_lds(
                (const __attribute__((address_space(1))) void*)gp,
                (__attribute__((address_space(3))) void*)lp, 16, 0, 0);
        }
        __syncthreads();
#pragma unroll
        for (int kh = 0; kh < 2; ++kh) {          // kk = kh*32
            int ch = ((kh << 2) + kg) ^ (lo & 7); // swizzled chunk (row&7 == lo&7)
            bf16x8 a[4], b[4];
#pragma unroll
            for (int i = 0; i < 4; ++i) a[i] = *(const bf16x8*)&As[wy + i * 16 + lo][ch * 8];
#pragma unroll
            for (int j = 0; j < 4; ++j) b[j] = *(const bf16x8*)&Bs[wx + j * 16 + lo][ch * 8];
#pragma unroll
            for (int i = 0; i < 4; ++i)
#pragma unroll
                for (int j = 0; j < 4; ++j)
                    acc[i][j] = __builtin_amdgcn_mfma_f32_16x16x32_bf16(a[i], b[j], acc[i][j], 0, 0, 0);
        }
        __syncthreads();
    }

    // epilogue: C/D layout col=lane&15, row=(lane>>4)*4+reg (m89-verified)
    // arg = -ccl*max(L2,0) = min(2ccl*acc - ccl*(sqi+sqj), 0); kernel = sum u^(2^i)
    int gi0 = I0 + wy + kg * 4;
    int gj0 = J0 + wx + lo;
    float nsic[4][4], nsjc[4];
#pragma unroll
    for (int i = 0; i < 4; ++i)
#pragma unroll
        for (int r = 0; r < 4; ++r) nsic[i][r] = -ccl * sq[gi0 + i * 16 + r];
#pragma unroll
    for (int j = 0; j < 4; ++j) nsjc[j] = -ccl * sq[gj0 + j * 16];
    const float cc2 = 2.f * ccl;

    float sgn  = ((bi < NT / 2) == (bj < NT / 2)) ? 1.f : -1.f;
    float tsum = 0.f;
    if (bi != bj) {
#pragma unroll
        for (int i = 0; i < 4; ++i)
#pragma unroll
            for (int j = 0; j < 4; ++j)
#pragma unroll
                for (int r = 0; r < 4; ++r) {
                    float arg = fminf(fmaf(cc2, acc[i][j][r], nsic[i][r]) + nsjc[j], 0.f);
                    float u   = exp2f(arg);
                    float u2 = u * u, u4 = u2 * u2, u8 = u4 * u4, u16 = u8 * u8;
                    tsum += ((u + u2) + (u4 + u8)) + u16;
                }
        tsum *= 2.f;
    } else {
#pragma unroll
        for (int i = 0; i < 4; ++i)
#pragma unroll
            for (int j = 0; j < 4; ++j)
#pragma unroll
                for (int r = 0; r < 4; ++r) {
                    int gi = gi0 + i * 16 + r, gj = gj0 + j * 16;
                    float w = (gi < gj) ? 2.f : ((gi == gj) ? 1.f : 0.f);
                    float arg = fminf(fmaf(cc2, acc[i][j][r], nsic[i][r]) + nsjc[j], 0.f);
                    float u   = exp2f(arg);
                    float u2 = u * u, u4 = u2 * u2, u8 = u4 * u4, u16 = u8 * u8;
                    tsum += w * (((u + u2) + (u4 + u8)) + u16);
                }
    }
    tsum *= sgn;

#pragma unroll
    for (int off = 32; off; off >>= 1) tsum += __shfl_down(tsum, off, 64);
    if (lane == 0) wred[wid] = (double)tsum;
    __syncthreads();
    if (t == 0) accpart[blockIdx.x] = wred[0] + wred[1] + wred[2] + wred[3];  // plain store
}

// Pass 3: reduce 2080 block partials -> loss.
__global__ __launch_bounds__(256) void finalize_loss(
    const double* __restrict__ accpart, float* __restrict__ out) {
    __shared__ double red[4];
    int t = threadIdx.x, lane = t & 63, w = t >> 6;
    double s = 0.0;
    for (int i = t; i < NBLK; i += 256) s += accpart[i];
#pragma unroll
    for (int off = 32; off; off >>= 1) s += __shfl_down(s, off, 64);
    if (lane == 0) red[w] = s;
    __syncthreads();
    if (t == 0) {
        double tot = red[0] + red[1] + red[2] + red[3];
        out[0] = (float)(tot / ((double)HALF * (double)HALF));
    }
}

extern "C" void kernel_launch(void* const* d_in, const int* in_sizes, int n_in,
                              void* d_out, int out_size, void* d_ws, size_t ws_size,
                              hipStream_t stream) {
    const float* x = (const float*)d_in[0];   // label / genre_label unused

    int*      d_counter = (int*)d_ws;
    float*    d_ccl     = (float*)((char*)d_ws + 8);
    float*    d_sq      = (float*)((char*)d_ws + 1024);
    ushort_t* d_xb      = (ushort_t*)((char*)d_ws + 33792);
    float*    d_colpart = (float*)((char*)d_ws + 3179520);
    double*   d_sqpart  = (double*)((char*)d_ws + 3376128);
    double*   d_accpart = (double*)((char*)d_ws + 3378176);

    hipMemsetAsync(d_ws, 0, 1024, stream);   // zero counter (+slack)

    prep<<<NPREP, 256, 0, stream>>>(x, d_xb, d_sq, d_colpart, d_sqpart,
                                    d_counter, d_ccl);
    mmd_mfma<<<NBLK, 256, 0, stream>>>(d_xb, d_sq, d_ccl, d_accpart);
    finalize_loss<<<1, 256, 0, stream>>>(d_accpart, (float*)d_out);
}